// Round 11
// baseline (362.096 us; speedup 1.0000x reference)
//
#include <hip/hip_runtime.h>
#include <cmath>

// SplineNet: 2x SplineConv(D=128, deg-1 B-spline, 1-D pseudo) + linear head.
// Round 11: fused layer v2 — 32-node blocks (8 waves), wave = 1 n-frag x
// 2 m-frags (B-frags read once per 32 rows: half the L2 B-traffic), 16-deep
// gather ILP, 24 waves/CU (launch_bounds(512,6)), setprio around MFMA.

typedef __attribute__((ext_vector_type(8))) short bf16x8;
typedef __attribute__((ext_vector_type(4))) float f32x4;

static inline int cdiv(int a, int b) { return (a + b - 1) / b; }

__device__ __forceinline__ float bf2f(unsigned short u) {
  unsigned v = ((unsigned)u) << 16;
  return __builtin_bit_cast(float, v);
}
__device__ __forceinline__ unsigned short f2bf(float f) {
  unsigned u = __builtin_bit_cast(unsigned, f);
  u += 0x7FFFu + ((u >> 16) & 1u);
  return (unsigned short)(u >> 16);
}
__device__ __forceinline__ float elu1(float v) {
  return v > 0.f ? v : (expf(v) - 1.f);
}

__global__ void hist_kernel(const int* __restrict__ ei, int E,
                            int* __restrict__ cnt) {
  int e = blockIdx.x * blockDim.x + threadIdx.x;
  if (e < E) atomicAdd(&cnt[ei[E + e]], 1);
}

// ---- three-phase device-wide exclusive scan over cnt[N] ----
__global__ void scan_partials_kernel(const int* __restrict__ cnt, int N,
                                     int* __restrict__ partials) {
  __shared__ int red[256];
  int base = blockIdx.x * 1024;
  int s = 0;
  for (int i = threadIdx.x; i < 1024; i += 256) {
    int idx = base + i;
    if (idx < N) s += cnt[idx];
  }
  red[threadIdx.x] = s;
  __syncthreads();
  for (int off = 128; off > 0; off >>= 1) {
    if (threadIdx.x < off) red[threadIdx.x] += red[threadIdx.x + off];
    __syncthreads();
  }
  if (threadIdx.x == 0) partials[blockIdx.x] = red[0];
}

__global__ void scan_pscan_kernel(const int* __restrict__ partials, int nb,
                                  int* __restrict__ pscan) {
  __shared__ int tmp[256];
  int t = threadIdx.x;
  int v = (t < nb) ? partials[t] : 0;
  tmp[t] = v;
  __syncthreads();
  for (int off = 1; off < 256; off <<= 1) {
    int u = (t >= off) ? tmp[t - off] : 0;
    __syncthreads();
    tmp[t] += u;
    __syncthreads();
  }
  pscan[t + 1] = tmp[t];
  if (t == 0) pscan[0] = 0;
}

__global__ void scan_apply_kernel(const int* __restrict__ cnt, int N,
                                  const int* __restrict__ pscan, int nb,
                                  int* __restrict__ rowptr, int* __restrict__ cursor) {
  __shared__ int tsum[256];
  int t = threadIdx.x;
  int base = blockIdx.x * 1024 + t * 4;
  int v0 = 0, v1 = 0, v2 = 0, v3 = 0;
  if (base + 0 < N) v0 = cnt[base + 0];
  if (base + 1 < N) v1 = cnt[base + 1];
  if (base + 2 < N) v2 = cnt[base + 2];
  if (base + 3 < N) v3 = cnt[base + 3];
  int s = v0 + v1 + v2 + v3;
  tsum[t] = s;
  __syncthreads();
  for (int off = 1; off < 256; off <<= 1) {
    int u = (t >= off) ? tsum[t - off] : 0;
    __syncthreads();
    tsum[t] += u;
    __syncthreads();
  }
  int excl = pscan[blockIdx.x] + tsum[t] - s;
  if (base + 0 < N) { rowptr[base + 0] = excl; cursor[base + 0] = excl; excl += v0; }
  if (base + 1 < N) { rowptr[base + 1] = excl; cursor[base + 1] = excl; excl += v1; }
  if (base + 2 < N) { rowptr[base + 2] = excl; cursor[base + 2] = excl; excl += v2; }
  if (base + 3 < N) { rowptr[base + 3] = excl; cursor[base + 3] = excl; excl += v3; }
  if (blockIdx.x == 0 && t == 0) rowptr[N] = pscan[nb];
}

// scatter edges into CSR order; pack (src, p) as int2
__global__ void scatter_kernel(const int* __restrict__ ei,
                               const float* __restrict__ ea, int E,
                               int* __restrict__ cursor, int2* __restrict__ es) {
  int e = blockIdx.x * blockDim.x + threadIdx.x;
  if (e < E) {
    int dst = ei[E + e];
    int pos = atomicAdd(&cursor[dst], 1);
    es[pos] = make_int2(ei[e], __float_as_int(ea[e]));
  }
}

// x (f32 [N][128]) -> compact bf16 xb[N][128]
__global__ void cvt_x_kernel(const float* __restrict__ x,
                             unsigned short* __restrict__ xb, int n4) {
  for (int i = blockIdx.x * blockDim.x + threadIdx.x; i < n4;
       i += gridDim.x * blockDim.x) {
    float4 v = ((const float4*)x)[i];
    ushort4 o;
    o.x = f2bf(v.x); o.y = f2bf(v.y); o.z = f2bf(v.z); o.w = f2bf(v.w);
    ((ushort4*)xb)[i] = o;
  }
}

// Build B in MFMA-fragment order: BtF[frag G][lane][8] where G = ks*8+ni,
// col = ni*16+(lane&15), k = ks*32+(lane>>4)*8+j ; B[k][col] = k<KD?W:root.
__global__ void build_btf_kernel(const float* __restrict__ W,
                                 const float* __restrict__ root,
                                 unsigned short* __restrict__ BtF, int KD, int KT) {
  int idx = blockIdx.x * blockDim.x + threadIdx.x;
  if (idx >= 128 * KT) return;
  int G = idx >> 9;
  int r = idx & 511;
  int lane = r >> 3;
  int j = r & 7;
  int ks = G >> 3;
  int ni = G & 7;
  int col = ni * 16 + (lane & 15);
  int k = ks * 32 + (lane >> 4) * 8 + j;
  float v = (k < KD) ? W[(size_t)k * 128 + col] : root[(size_t)(k - KD) * 128 + col];
  BtF[idx] = f2bf(v);
}

// one 16-slot chunk of the per-node edge loop; MASK handles the tail
// (clamped addresses -> L1 hits, weights zeroed).
template <int K, bool MASK>
__device__ __forceinline__ void agg_chunk16(
    const unsigned short* __restrict__ Xc, const int2* __restrict__ es,
    int e, int end, int lane, float (&accx)[K], float (&accy)[K]) {
  const int last = end - 1;
  int sx[16];
  float pv[16];
#pragma unroll
  for (int t = 0; t < 16; ++t) {
    int idx = MASK ? min(e + t, last) : (e + t);
    int2 sp = es[idx];
    sx[t] = sp.x;
    pv[t] = __int_as_float(sp.y);
  }
  unsigned int dv[16];
#pragma unroll
  for (int t = 0; t < 16; ++t)
    dv[t] = *(const unsigned int*)(Xc + (size_t)sx[t] * 128 + 2 * lane);
#pragma unroll
  for (int t = 0; t < 16; ++t) {
    float v = pv[t] * (float)(K - 1);
    int i0 = min((int)v, K - 2);
    float fr = v - (float)i0;
    float w0 = 1.f - fr;
    if (MASK) {
      bool ok = (e + t <= last);
      fr = ok ? fr : 0.f;
      w0 = ok ? w0 : 0.f;
    }
    float xx = __builtin_bit_cast(float, dv[t] << 16);
    float xy = __builtin_bit_cast(float, dv[t] & 0xffff0000u);
    int i0u = __builtin_amdgcn_readfirstlane(i0);
#pragma unroll
    for (int k = 0; k < K - 1; ++k) {
      if (i0u == k) {
        accx[k] = fmaf(w0, xx, accx[k]);
        accy[k] = fmaf(w0, xy, accy[k]);
        accx[k + 1] = fmaf(fr, xx, accx[k + 1]);
        accy[k + 1] = fmaf(fr, xy, accy[k + 1]);
      }
    }
  }
}

// FUSED layer v2: block = 8 waves = 32 nodes (wave aggregates 4 nodes ->
// LDS tile Asub[32][KT+8]), barrier, MFMA (wave = n-frag w x 2 m-frags;
// each B-frag read once per block). !FINAL -> compact Hout[N][128].
// FINAL -> head fused, FOut[N][2].
template <int K, int KT, bool FINAL>
__global__ __launch_bounds__(512, 6) void fused_layer(
    const unsigned short* __restrict__ Xc,
    const int* __restrict__ rowptr, const int2* __restrict__ es,
    const unsigned short* __restrict__ BtF,
    const float* __restrict__ bias,
    unsigned short* __restrict__ Hout,
    const float* __restrict__ Wm, const float* __restrict__ bm,
    float* __restrict__ FOut, int N) {
  constexpr int LDK = KT + 8;
  constexpr int NKS = KT / 32;
  __shared__ unsigned short Asub[32][LDK];
  __shared__ float hred[8][32][2];

  const int w = threadIdx.x >> 6;
  const int lane = threadIdx.x & 63;
  const int lr = lane & 15;
  const int kg = lane >> 4;
  const int node0 = blockIdx.x * 32;

  // ---- agg phase: wave w aggregates rows w*4 .. w*4+3 ----
  for (int i = 0; i < 4; ++i) {
    const int r = w * 4 + i;
    const int node = min(node0 + r, N - 1);
    float accx[K], accy[K];
#pragma unroll
    for (int k = 0; k < K; ++k) { accx[k] = 0.f; accy[k] = 0.f; }
    const int beg = rowptr[node], end = rowptr[node + 1];
    int e = beg;
    for (; e + 16 <= end; e += 16)
      agg_chunk16<K, false>(Xc, es, e, end, lane, accx, accy);
    if (e < end)
      agg_chunk16<K, true>(Xc, es, e, end, lane, accx, accy);
    float deg = (float)(end - beg);
    float sc = 1.f / fmaxf(deg, 1.f);
#pragma unroll
    for (int k = 0; k < K; ++k) {
      ushort2 o;
      o.x = f2bf(accx[k] * sc);
      o.y = f2bf(accy[k] * sc);
      *(ushort2*)&Asub[r][k * 128 + 2 * lane] = o;
    }
    ushort2 own = *(const ushort2*)(Xc + (size_t)node * 128 + 2 * lane);
    *(ushort2*)&Asub[r][K * 128 + 2 * lane] = own;
  }
  __syncthreads();

  // ---- MFMA phase: wave w = n-frag w (cols w*16..+15) x 2 m-frags ----
  const int ni = w;
  f32x4 acc0 = {0.f, 0.f, 0.f, 0.f};
  f32x4 acc1 = {0.f, 0.f, 0.f, 0.f};
  __builtin_amdgcn_s_setprio(1);
#pragma unroll
  for (int ks = 0; ks < NKS; ++ks) {
    bf16x8 b = *(const bf16x8*)(BtF + (size_t)(ks * 8 + ni) * 512 + lane * 8);
    bf16x8 a0 = *(const bf16x8*)&Asub[lr][ks * 32 + kg * 8];
    bf16x8 a1 = *(const bf16x8*)&Asub[16 + lr][ks * 32 + kg * 8];
    acc0 = __builtin_amdgcn_mfma_f32_16x16x32_bf16(a0, b, acc0, 0, 0, 0);
    acc1 = __builtin_amdgcn_mfma_f32_16x16x32_bf16(a1, b, acc1, 0, 0, 0);
  }
  __builtin_amdgcn_s_setprio(0);

  const float bv = bias[ni * 16 + lr];

  if constexpr (!FINAL) {
#pragma unroll
    for (int mf = 0; mf < 2; ++mf) {
      f32x4 a = mf ? acc1 : acc0;
#pragma unroll
      for (int r = 0; r < 4; ++r) {
        int node = node0 + mf * 16 + kg * 4 + r;
        if (node < N) {
          float h = elu1(a[r] + bv);
          Hout[(size_t)node * 128 + ni * 16 + lr] = f2bf(h);
        }
      }
    }
  } else {
    float2 wv = *(const float2*)&Wm[(ni * 16 + lr) * 2];
#pragma unroll
    for (int mf = 0; mf < 2; ++mf) {
      f32x4 a = mf ? acc1 : acc0;
#pragma unroll
      for (int r = 0; r < 4; ++r) {
        float h = elu1(a[r] + bv);
        float t0 = h * wv.x;
        float t1 = h * wv.y;
#pragma unroll
        for (int off = 8; off > 0; off >>= 1) {
          t0 += __shfl_down(t0, off);
          t1 += __shfl_down(t1, off);
        }
        if (lr == 0) {
          hred[w][mf * 16 + kg * 4 + r][0] = t0;
          hred[w][mf * 16 + kg * 4 + r][1] = t1;
        }
      }
    }
    __syncthreads();
    if (threadIdx.x < 64) {
      int row = threadIdx.x >> 1;
      int c = threadIdx.x & 1;
      int node = node0 + row;
      if (node < N) {
        float s = bm[c];
#pragma unroll
        for (int ww = 0; ww < 8; ++ww) s += hred[ww][row][c];
        FOut[(size_t)node * 2 + c] = fmaxf(s, 0.f);
      }
    }
  }
}

extern "C" void kernel_launch(void* const* d_in, const int* in_sizes, int n_in,
                              void* d_out, int out_size, void* d_ws, size_t ws_size,
                              hipStream_t stream) {
  const float* x = (const float*)d_in[0];
  const int* ei = (const int*)d_in[1];
  const float* ea = (const float*)d_in[2];
  const float* W1 = (const float*)d_in[3];
  const float* root1 = (const float*)d_in[4];
  const float* b1 = (const float*)d_in[5];
  const float* W2 = (const float*)d_in[6];
  const float* root2 = (const float*)d_in[7];
  const float* b2 = (const float*)d_in[8];
  const float* Wm = (const float*)d_in[9];
  const float* bm = (const float*)d_in[10];
  const int N = in_sizes[0] / 128;
  const int E = in_sizes[2];
  const int KT1 = 512, KT2 = 768;
  const int nb = cdiv(N, 1024);

  char* base = (char*)d_ws;
  size_t off = 0;
  auto alloc = [&](size_t bytes) -> void* {
    void* p = base + off;
    off += (bytes + 255) & ~(size_t)255;
    return p;
  };
  int* cnt = (int*)alloc((size_t)N * 4);
  int* rowptr = (int*)alloc((size_t)(N + 1) * 4);
  int* cursor = (int*)alloc((size_t)N * 4);
  int* partials = (int*)alloc(256 * 4);
  int* pscan = (int*)alloc(257 * 4);
  int2* es = (int2*)alloc((size_t)E * 8);
  unsigned short* xb = (unsigned short*)alloc((size_t)N * 128 * 2);
  unsigned short* h1 = (unsigned short*)alloc((size_t)N * 128 * 2);
  unsigned short* BtF1 = (unsigned short*)alloc((size_t)128 * KT1 * 2);
  unsigned short* BtF2 = (unsigned short*)alloc((size_t)128 * KT2 * 2);
  (void)ws_size; (void)n_in; (void)out_size;

  // CSR build (dst bins)
  hipMemsetAsync(cnt, 0, (size_t)N * 4, stream);
  hist_kernel<<<cdiv(E, 256), 256, 0, stream>>>(ei, E, cnt);
  scan_partials_kernel<<<nb, 256, 0, stream>>>(cnt, N, partials);
  scan_pscan_kernel<<<1, 256, 0, stream>>>(partials, nb, pscan);
  scan_apply_kernel<<<nb, 256, 0, stream>>>(cnt, N, pscan, nb, rowptr, cursor);
  scatter_kernel<<<cdiv(E, 256), 256, 0, stream>>>(ei, ea, E, cursor, es);

  // weights -> fragment-order bf16
  build_btf_kernel<<<cdiv(128 * KT1, 256), 256, 0, stream>>>(W1, root1, BtF1, 384, KT1);
  build_btf_kernel<<<cdiv(128 * KT2, 256), 256, 0, stream>>>(W2, root2, BtF2, 640, KT2);

  // x -> compact bf16 xb
  cvt_x_kernel<<<2048, 256, 0, stream>>>(x, xb, N * 32);

  const int nblk = cdiv(N, 32);
  // layer 1 (K=3): fused agg+GEMM -> compact h1
  fused_layer<3, 512, false><<<nblk, 512, 0, stream>>>(
      xb, rowptr, es, BtF1, b1, h1, nullptr, nullptr, nullptr, N);
  // layer 2 (K=5): fused agg+GEMM+head -> out
  fused_layer<5, 768, true><<<nblk, 512, 0, stream>>>(
      h1, rowptr, es, BtF2, b2, nullptr, Wm, bm, (float*)d_out, N);
}

// Round 12
// 315.914 us; speedup vs baseline: 1.1462x; 1.1462x over previous
//
#include <hip/hip_runtime.h>
#include <cmath>

// SplineNet: 2x SplineConv(D=128, deg-1 B-spline, 1-D pseudo) + linear head.
// Round 12: fused v2 minus the spill. r11's 16-deep chunk arrays spilled to
// scratch under the forced 40-VGPR cap (WRITE_SIZE 0.4->88MB). Now: 8-deep
// unmasked chunks + masked-4 tail (r10-proven register footprint),
// launch_bounds(512,4) so LDS (not VGPR) sets occupancy, hred only in FINAL.

typedef __attribute__((ext_vector_type(8))) short bf16x8;
typedef __attribute__((ext_vector_type(4))) float f32x4;

static inline int cdiv(int a, int b) { return (a + b - 1) / b; }

__device__ __forceinline__ float bf2f(unsigned short u) {
  unsigned v = ((unsigned)u) << 16;
  return __builtin_bit_cast(float, v);
}
__device__ __forceinline__ unsigned short f2bf(float f) {
  unsigned u = __builtin_bit_cast(unsigned, f);
  u += 0x7FFFu + ((u >> 16) & 1u);
  return (unsigned short)(u >> 16);
}
__device__ __forceinline__ float elu1(float v) {
  return v > 0.f ? v : (expf(v) - 1.f);
}

__global__ void hist_kernel(const int* __restrict__ ei, int E,
                            int* __restrict__ cnt) {
  int e = blockIdx.x * blockDim.x + threadIdx.x;
  if (e < E) atomicAdd(&cnt[ei[E + e]], 1);
}

// ---- three-phase device-wide exclusive scan over cnt[N] ----
__global__ void scan_partials_kernel(const int* __restrict__ cnt, int N,
                                     int* __restrict__ partials) {
  __shared__ int red[256];
  int base = blockIdx.x * 1024;
  int s = 0;
  for (int i = threadIdx.x; i < 1024; i += 256) {
    int idx = base + i;
    if (idx < N) s += cnt[idx];
  }
  red[threadIdx.x] = s;
  __syncthreads();
  for (int off = 128; off > 0; off >>= 1) {
    if (threadIdx.x < off) red[threadIdx.x] += red[threadIdx.x + off];
    __syncthreads();
  }
  if (threadIdx.x == 0) partials[blockIdx.x] = red[0];
}

__global__ void scan_pscan_kernel(const int* __restrict__ partials, int nb,
                                  int* __restrict__ pscan) {
  __shared__ int tmp[256];
  int t = threadIdx.x;
  int v = (t < nb) ? partials[t] : 0;
  tmp[t] = v;
  __syncthreads();
  for (int off = 1; off < 256; off <<= 1) {
    int u = (t >= off) ? tmp[t - off] : 0;
    __syncthreads();
    tmp[t] += u;
    __syncthreads();
  }
  pscan[t + 1] = tmp[t];
  if (t == 0) pscan[0] = 0;
}

__global__ void scan_apply_kernel(const int* __restrict__ cnt, int N,
                                  const int* __restrict__ pscan, int nb,
                                  int* __restrict__ rowptr, int* __restrict__ cursor) {
  __shared__ int tsum[256];
  int t = threadIdx.x;
  int base = blockIdx.x * 1024 + t * 4;
  int v0 = 0, v1 = 0, v2 = 0, v3 = 0;
  if (base + 0 < N) v0 = cnt[base + 0];
  if (base + 1 < N) v1 = cnt[base + 1];
  if (base + 2 < N) v2 = cnt[base + 2];
  if (base + 3 < N) v3 = cnt[base + 3];
  int s = v0 + v1 + v2 + v3;
  tsum[t] = s;
  __syncthreads();
  for (int off = 1; off < 256; off <<= 1) {
    int u = (t >= off) ? tsum[t - off] : 0;
    __syncthreads();
    tsum[t] += u;
    __syncthreads();
  }
  int excl = pscan[blockIdx.x] + tsum[t] - s;
  if (base + 0 < N) { rowptr[base + 0] = excl; cursor[base + 0] = excl; excl += v0; }
  if (base + 1 < N) { rowptr[base + 1] = excl; cursor[base + 1] = excl; excl += v1; }
  if (base + 2 < N) { rowptr[base + 2] = excl; cursor[base + 2] = excl; excl += v2; }
  if (base + 3 < N) { rowptr[base + 3] = excl; cursor[base + 3] = excl; excl += v3; }
  if (blockIdx.x == 0 && t == 0) rowptr[N] = pscan[nb];
}

// scatter edges into CSR order; pack (src, p) as int2
__global__ void scatter_kernel(const int* __restrict__ ei,
                               const float* __restrict__ ea, int E,
                               int* __restrict__ cursor, int2* __restrict__ es) {
  int e = blockIdx.x * blockDim.x + threadIdx.x;
  if (e < E) {
    int dst = ei[E + e];
    int pos = atomicAdd(&cursor[dst], 1);
    es[pos] = make_int2(ei[e], __float_as_int(ea[e]));
  }
}

// x (f32 [N][128]) -> compact bf16 xb[N][128]
__global__ void cvt_x_kernel(const float* __restrict__ x,
                             unsigned short* __restrict__ xb, int n4) {
  for (int i = blockIdx.x * blockDim.x + threadIdx.x; i < n4;
       i += gridDim.x * blockDim.x) {
    float4 v = ((const float4*)x)[i];
    ushort4 o;
    o.x = f2bf(v.x); o.y = f2bf(v.y); o.z = f2bf(v.z); o.w = f2bf(v.w);
    ((ushort4*)xb)[i] = o;
  }
}

// Build B in MFMA-fragment order: BtF[frag G][lane][8] where G = ks*8+ni,
// col = ni*16+(lane&15), k = ks*32+(lane>>4)*8+j ; B[k][col] = k<KD?W:root.
__global__ void build_btf_kernel(const float* __restrict__ W,
                                 const float* __restrict__ root,
                                 unsigned short* __restrict__ BtF, int KD, int KT) {
  int idx = blockIdx.x * blockDim.x + threadIdx.x;
  if (idx >= 128 * KT) return;
  int G = idx >> 9;
  int r = idx & 511;
  int lane = r >> 3;
  int j = r & 7;
  int ks = G >> 3;
  int ni = G & 7;
  int col = ni * 16 + (lane & 15);
  int k = ks * 32 + (lane >> 4) * 8 + j;
  float v = (k < KD) ? W[(size_t)k * 128 + col] : root[(size_t)(k - KD) * 128 + col];
  BtF[idx] = f2bf(v);
}

// 8 unmasked edge slots
template <int K>
__device__ __forceinline__ void agg_chunk8(
    const unsigned short* __restrict__ Xc, const int2* __restrict__ es,
    int e, int lane, float (&accx)[K], float (&accy)[K]) {
  int2 sp[8];
#pragma unroll
  for (int t = 0; t < 8; ++t) sp[t] = es[e + t];
  unsigned int dv[8];
#pragma unroll
  for (int t = 0; t < 8; ++t)
    dv[t] = *(const unsigned int*)(Xc + (size_t)sp[t].x * 128 + 2 * lane);
#pragma unroll
  for (int t = 0; t < 8; ++t) {
    float v = __int_as_float(sp[t].y) * (float)(K - 1);
    int i0 = min((int)v, K - 2);
    float fr = v - (float)i0;
    float w0 = 1.f - fr;
    float xx = __builtin_bit_cast(float, dv[t] << 16);
    float xy = __builtin_bit_cast(float, dv[t] & 0xffff0000u);
    int i0u = __builtin_amdgcn_readfirstlane(i0);
#pragma unroll
    for (int k = 0; k < K - 1; ++k) {
      if (i0u == k) {
        accx[k] = fmaf(w0, xx, accx[k]);
        accy[k] = fmaf(w0, xy, accy[k]);
        accx[k + 1] = fmaf(fr, xx, accx[k + 1]);
        accy[k + 1] = fmaf(fr, xy, accy[k + 1]);
      }
    }
  }
}

// 4 masked edge slots (clamped addr -> L1 hit, weights zeroed)
template <int K>
__device__ __forceinline__ void agg_chunk4m(
    const unsigned short* __restrict__ Xc, const int2* __restrict__ es,
    int e, int end, int lane, float (&accx)[K], float (&accy)[K]) {
  const int last = end - 1;
  int2 sp[4];
  bool okv[4];
#pragma unroll
  for (int t = 0; t < 4; ++t) {
    okv[t] = (e + t <= last);
    sp[t] = es[okv[t] ? (e + t) : last];
  }
  unsigned int dv[4];
#pragma unroll
  for (int t = 0; t < 4; ++t)
    dv[t] = *(const unsigned int*)(Xc + (size_t)sp[t].x * 128 + 2 * lane);
#pragma unroll
  for (int t = 0; t < 4; ++t) {
    float v = __int_as_float(sp[t].y) * (float)(K - 1);
    int i0 = min((int)v, K - 2);
    float fr = v - (float)i0;
    float w0 = 1.f - fr;
    if (!okv[t]) { w0 = 0.f; fr = 0.f; }
    float xx = __builtin_bit_cast(float, dv[t] << 16);
    float xy = __builtin_bit_cast(float, dv[t] & 0xffff0000u);
    int i0u = __builtin_amdgcn_readfirstlane(i0);
#pragma unroll
    for (int k = 0; k < K - 1; ++k) {
      if (i0u == k) {
        accx[k] = fmaf(w0, xx, accx[k]);
        accy[k] = fmaf(w0, xy, accy[k]);
        accx[k + 1] = fmaf(fr, xx, accx[k + 1]);
        accy[k + 1] = fmaf(fr, xy, accy[k + 1]);
      }
    }
  }
}

// FUSED layer v2: block = 8 waves = 32 nodes (wave aggregates 4 nodes ->
// LDS tile Asub[32][KT+8]), barrier, MFMA (wave = n-frag w x 2 m-frags;
// each B-frag read once per block). !FINAL -> compact Hout[N][128].
// FINAL -> head fused, FOut[N][2].
template <int K, int KT, bool FINAL>
__global__ __launch_bounds__(512, 4) void fused_layer(
    const unsigned short* __restrict__ Xc,
    const int* __restrict__ rowptr, const int2* __restrict__ es,
    const unsigned short* __restrict__ BtF,
    const float* __restrict__ bias,
    unsigned short* __restrict__ Hout,
    const float* __restrict__ Wm, const float* __restrict__ bm,
    float* __restrict__ FOut, int N) {
  constexpr int LDK = KT + 8;
  constexpr int NKS = KT / 32;
  __shared__ unsigned short Asub[32][LDK];

  const int w = threadIdx.x >> 6;
  const int lane = threadIdx.x & 63;
  const int lr = lane & 15;
  const int kg = lane >> 4;
  const int node0 = blockIdx.x * 32;

  // ---- agg phase: wave w aggregates rows w*4 .. w*4+3 ----
  for (int i = 0; i < 4; ++i) {
    const int r = w * 4 + i;
    const int node = min(node0 + r, N - 1);
    float accx[K], accy[K];
#pragma unroll
    for (int k = 0; k < K; ++k) { accx[k] = 0.f; accy[k] = 0.f; }
    const int beg = rowptr[node], end = rowptr[node + 1];
    int e = beg;
    for (; e + 8 <= end; e += 8)
      agg_chunk8<K>(Xc, es, e, lane, accx, accy);
    for (; e < end; e += 4)
      agg_chunk4m<K>(Xc, es, e, end, lane, accx, accy);
    float deg = (float)(end - beg);
    float sc = 1.f / fmaxf(deg, 1.f);
#pragma unroll
    for (int k = 0; k < K; ++k) {
      ushort2 o;
      o.x = f2bf(accx[k] * sc);
      o.y = f2bf(accy[k] * sc);
      *(ushort2*)&Asub[r][k * 128 + 2 * lane] = o;
    }
    ushort2 own = *(const ushort2*)(Xc + (size_t)node * 128 + 2 * lane);
    *(ushort2*)&Asub[r][K * 128 + 2 * lane] = own;
  }
  __syncthreads();

  // ---- MFMA phase: wave w = n-frag w (cols w*16..+15) x 2 m-frags ----
  const int ni = w;
  f32x4 acc0 = {0.f, 0.f, 0.f, 0.f};
  f32x4 acc1 = {0.f, 0.f, 0.f, 0.f};
  __builtin_amdgcn_s_setprio(1);
#pragma unroll
  for (int ks = 0; ks < NKS; ++ks) {
    bf16x8 b = *(const bf16x8*)(BtF + (size_t)(ks * 8 + ni) * 512 + lane * 8);
    bf16x8 a0 = *(const bf16x8*)&Asub[lr][ks * 32 + kg * 8];
    bf16x8 a1 = *(const bf16x8*)&Asub[16 + lr][ks * 32 + kg * 8];
    acc0 = __builtin_amdgcn_mfma_f32_16x16x32_bf16(a0, b, acc0, 0, 0, 0);
    acc1 = __builtin_amdgcn_mfma_f32_16x16x32_bf16(a1, b, acc1, 0, 0, 0);
  }
  __builtin_amdgcn_s_setprio(0);

  const float bv = bias[ni * 16 + lr];

  if constexpr (!FINAL) {
#pragma unroll
    for (int mf = 0; mf < 2; ++mf) {
      f32x4 a = mf ? acc1 : acc0;
#pragma unroll
      for (int r = 0; r < 4; ++r) {
        int node = node0 + mf * 16 + kg * 4 + r;
        if (node < N) {
          float h = elu1(a[r] + bv);
          Hout[(size_t)node * 128 + ni * 16 + lr] = f2bf(h);
        }
      }
    }
  } else {
    __shared__ float hred[8][32][2];
    float2 wv = *(const float2*)&Wm[(ni * 16 + lr) * 2];
#pragma unroll
    for (int mf = 0; mf < 2; ++mf) {
      f32x4 a = mf ? acc1 : acc0;
#pragma unroll
      for (int r = 0; r < 4; ++r) {
        float h = elu1(a[r] + bv);
        float t0 = h * wv.x;
        float t1 = h * wv.y;
#pragma unroll
        for (int off = 8; off > 0; off >>= 1) {
          t0 += __shfl_down(t0, off);
          t1 += __shfl_down(t1, off);
        }
        if (lr == 0) {
          hred[w][mf * 16 + kg * 4 + r][0] = t0;
          hred[w][mf * 16 + kg * 4 + r][1] = t1;
        }
      }
    }
    __syncthreads();
    if (threadIdx.x < 64) {
      int row = threadIdx.x >> 1;
      int c = threadIdx.x & 1;
      int node = node0 + row;
      if (node < N) {
        float s = bm[c];
#pragma unroll
        for (int ww = 0; ww < 8; ++ww) s += hred[ww][row][c];
        FOut[(size_t)node * 2 + c] = fmaxf(s, 0.f);
      }
    }
  }
}

extern "C" void kernel_launch(void* const* d_in, const int* in_sizes, int n_in,
                              void* d_out, int out_size, void* d_ws, size_t ws_size,
                              hipStream_t stream) {
  const float* x = (const float*)d_in[0];
  const int* ei = (const int*)d_in[1];
  const float* ea = (const float*)d_in[2];
  const float* W1 = (const float*)d_in[3];
  const float* root1 = (const float*)d_in[4];
  const float* b1 = (const float*)d_in[5];
  const float* W2 = (const float*)d_in[6];
  const float* root2 = (const float*)d_in[7];
  const float* b2 = (const float*)d_in[8];
  const float* Wm = (const float*)d_in[9];
  const float* bm = (const float*)d_in[10];
  const int N = in_sizes[0] / 128;
  const int E = in_sizes[2];
  const int KT1 = 512, KT2 = 768;
  const int nb = cdiv(N, 1024);

  char* base = (char*)d_ws;
  size_t off = 0;
  auto alloc = [&](size_t bytes) -> void* {
    void* p = base + off;
    off += (bytes + 255) & ~(size_t)255;
    return p;
  };
  int* cnt = (int*)alloc((size_t)N * 4);
  int* rowptr = (int*)alloc((size_t)(N + 1) * 4);
  int* cursor = (int*)alloc((size_t)N * 4);
  int* partials = (int*)alloc(256 * 4);
  int* pscan = (int*)alloc(257 * 4);
  int2* es = (int2*)alloc((size_t)E * 8);
  unsigned short* xb = (unsigned short*)alloc((size_t)N * 128 * 2);
  unsigned short* h1 = (unsigned short*)alloc((size_t)N * 128 * 2);
  unsigned short* BtF1 = (unsigned short*)alloc((size_t)128 * KT1 * 2);
  unsigned short* BtF2 = (unsigned short*)alloc((size_t)128 * KT2 * 2);
  (void)ws_size; (void)n_in; (void)out_size;

  // CSR build (dst bins)
  hipMemsetAsync(cnt, 0, (size_t)N * 4, stream);
  hist_kernel<<<cdiv(E, 256), 256, 0, stream>>>(ei, E, cnt);
  scan_partials_kernel<<<nb, 256, 0, stream>>>(cnt, N, partials);
  scan_pscan_kernel<<<1, 256, 0, stream>>>(partials, nb, pscan);
  scan_apply_kernel<<<nb, 256, 0, stream>>>(cnt, N, pscan, nb, rowptr, cursor);
  scatter_kernel<<<cdiv(E, 256), 256, 0, stream>>>(ei, ea, E, cursor, es);

  // weights -> fragment-order bf16
  build_btf_kernel<<<cdiv(128 * KT1, 256), 256, 0, stream>>>(W1, root1, BtF1, 384, KT1);
  build_btf_kernel<<<cdiv(128 * KT2, 256), 256, 0, stream>>>(W2, root2, BtF2, 640, KT2);

  // x -> compact bf16 xb
  cvt_x_kernel<<<2048, 256, 0, stream>>>(x, xb, N * 32);

  const int nblk = cdiv(N, 32);
  // layer 1 (K=3): fused agg+GEMM -> compact h1
  fused_layer<3, 512, false><<<nblk, 512, 0, stream>>>(
      xb, rowptr, es, BtF1, b1, h1, nullptr, nullptr, nullptr, N);
  // layer 2 (K=5): fused agg+GEMM+head -> out
  fused_layer<5, 768, true><<<nblk, 512, 0, stream>>>(
      h1, rowptr, es, BtF2, b2, nullptr, Wm, bm, (float*)d_out, N);
}